// Round 1
// baseline (311.189 us; speedup 1.0000x reference)
//
#include <hip/hip_runtime.h>
#include <hip/hip_bf16.h>

#define NPTS   2048
#define IDIM   16
#define HDIM   32
#define CUTSN  8
#define EPSV   1e-5f
#define PSCALE 0.07856742013183862f   /* 1/(sqrt(2)*9) */

__device__ __forceinline__ float leaky(float x) { return x >= 0.f ? x : 0.2f * x; }

/* ---------------- two-layer MLP (per-row), K = input dim ---------------- */
template <int K>
__global__ __launch_bounds__(256) void net2_kernel(
    const float* __restrict__ xin,
    const float* __restrict__ W1, const float* __restrict__ b1,
    const float* __restrict__ W2, const float* __restrict__ b2,
    float* __restrict__ out)
{
    int i = blockIdx.x * 256 + threadIdx.x;   // row
    float x[K];
#pragma unroll
    for (int k = 0; k < K; ++k) x[k] = xin[i * K + k];

    float y[HDIM];
#pragma unroll
    for (int h = 0; h < HDIM; ++h) {
        float v = b1[h];
#pragma unroll
        for (int k = 0; k < K; ++k) v = fmaf(x[k], W1[h * K + k], v);
        y[h] = leaky(v);
    }
#pragma unroll
    for (int h = 0; h < HDIM; ++h) {
        float v = b2[h];
#pragma unroll
        for (int k = 0; k < HDIM; ++k) v = fmaf(y[k], W2[h * HDIM + k], v);
        out[i * HDIM + h] = leaky(v);
    }
}

/* ---------------- GroupNorm stats: one block per group ---------------- */
__global__ __launch_bounds__(256) void gn_stats_kernel(
    const float* __restrict__ x, float* __restrict__ stats /* mu[4], rs[4] */)
{
    int g = blockIdx.x;
    float sum = 0.f, ss = 0.f;
    for (int i = threadIdx.x; i < NPTS; i += 256) {
        const float* p = x + i * HDIM + g * 8;
#pragma unroll
        for (int c = 0; c < 8; ++c) { float v = p[c]; sum += v; ss = fmaf(v, v, ss); }
    }
#pragma unroll
    for (int off = 32; off; off >>= 1) {
        sum += __shfl_down(sum, off, 64);
        ss  += __shfl_down(ss,  off, 64);
    }
    __shared__ float ls[4], lss[4];
    int wv = threadIdx.x >> 6, ln = threadIdx.x & 63;
    if (ln == 0) { ls[wv] = sum; lss[wv] = ss; }
    __syncthreads();
    if (threadIdx.x == 0) {
        float s = ls[0] + ls[1] + ls[2] + ls[3];
        float q = lss[0] + lss[1] + lss[2] + lss[3];
        float inv = 1.f / (8.f * NPTS);
        float mu = s * inv;
        float var = q * inv - mu * mu;
        stats[g]     = mu;
        stats[4 + g] = rsqrtf(var + EPSV);
    }
}

/* ------------- GroupNorm apply (+ optional zero of another buffer) ------------- */
__global__ __launch_bounds__(256) void gn_apply_kernel(
    const float* __restrict__ x, const float* __restrict__ stats,
    const float* __restrict__ gw, const float* __restrict__ gb,
    float* __restrict__ out, float* __restrict__ zbuf)
{
    int idx = blockIdx.x * 256 + threadIdx.x;   // < NPTS*HDIM
    int c = idx & (HDIM - 1);
    int g = c >> 3;
    out[idx] = fmaf((x[idx] - stats[g]) * stats[4 + g], gw[c], gb[c]);
    if (zbuf) zbuf[idx] = 0.f;
}

/* ---------------- the N^2 pairwise kernel ----------------
 * grid (16, 32): blockIdx.y -> 64-row i-chunk, blockIdx.x -> 128-col j-chunk.
 * 256 threads = 4 waves; lane = i (within chunk), wave = j-subchunk of 32.
 * j is wave-uniform -> all j-side loads become s_load (scalar pipe).    */
__global__ __launch_bounds__(256, 2) void pairwise_kernel(
    const float* __restrict__ points, const float* __restrict__ nuv,
    const float* __restrict__ A1, const float* __restrict__ B1,
    const float* __restrict__ A2, const float* __restrict__ B2,
    const float* __restrict__ fin, float* __restrict__ fout)
{
    const int lane = threadIdx.x & 63;
    const int wave = __builtin_amdgcn_readfirstlane(threadIdx.x >> 6);
    const int i  = blockIdx.y * 64 + lane;
    const int j0 = blockIdx.x * 128 + wave * 32;

    /* i-side (per lane) */
    const float pix = points[i * 3 + 0] * PSCALE;
    const float piy = points[i * 3 + 1] * PSCALE;
    const float piz = points[i * 3 + 2] * PSCALE;
    float nv[9];
#pragma unroll
    for (int k = 0; k < 9; ++k) nv[k] = nuv[i * 9 + k];

    float acc[HDIM];
#pragma unroll
    for (int h = 0; h < HDIM; ++h) acc[h] = 0.f;

    for (int jj = 0; jj < 32; ++jj) {
        const int j = j0 + jj;                       /* wave-uniform */
        const float dx = fmaf(points[j * 3 + 0], PSCALE, -pix);
        const float dy = fmaf(points[j * 3 + 1], PSCALE, -piy);
        const float dz = fmaf(points[j * 3 + 2], PSCALE, -piz);
        const float sq = dx * dx + dy * dy + dz * dz;
        const float dot = nv[0] * nuv[j * 9 + 0] + nv[1] * nuv[j * 9 + 1] + nv[2] * nuv[j * 9 + 2];
        const float tt = 2.f - dot;
        const float w  = __expf(-sq * tt * tt);

        const float X0 = nv[0] * dx + nv[1] * dy + nv[2] * dz;
        const float X1 = nv[3] * dx + nv[4] * dy + nv[5] * dz;
        const float X2 = nv[6] * dx + nv[7] * dy + nv[8] * dz;

        float u[CUTSN];
#pragma unroll
        for (int c = 0; c < CUTSN; ++c) {
            float v = fmaf(X0, A1[c * 3 + 0],
                      fmaf(X1, A1[c * 3 + 1],
                      fmaf(X2, A1[c * 3 + 2], B1[c])));
            u[c] = fmaxf(v, 0.f);
        }
#pragma unroll
        for (int h = 0; h < HDIM; ++h) {
            float v = B2[h];
#pragma unroll
            for (int c = 0; c < CUTSN; ++c) v = fmaf(u[c], A2[h * CUTSN + c], v);
            v = fmaxf(v, 0.f);
            acc[h] = fmaf(w * v, fin[j * HDIM + h], acc[h]);
        }
    }

    /* reduce the 4 waves' partial sums (they share the same 64 i's) */
    __shared__ float red[4][64][HDIM + 1];          /* +1 pad: avoid bank conflicts */
#pragma unroll
    for (int h = 0; h < HDIM; ++h) red[wave][lane][h] = acc[h];
    __syncthreads();

#pragma unroll
    for (int c8 = 0; c8 < 8; ++c8) {
        const int cell = threadIdx.x * 8 + c8;      /* 2048 cells = 64 i x 32 h */
        const int il = cell >> 5, h = cell & 31;
        const float v = red[0][il][h] + red[1][il][h] + red[2][il][h] + red[3][il][h];
        atomicAdd(&fout[(blockIdx.y * 64 + il) * HDIM + h], v);
    }
}

extern "C" void kernel_launch(void* const* d_in, const int* in_sizes, int n_in,
                              void* d_out, int out_size, void* d_ws, size_t ws_size,
                              hipStream_t stream)
{
    const float* points   = (const float*)d_in[0];
    const float* nuv      = (const float*)d_in[1];
    const float* features = (const float*)d_in[2];
    const float* W_in1    = (const float*)d_in[3];
    const float* b_in1    = (const float*)d_in[4];
    const float* W_in2    = (const float*)d_in[5];
    const float* b_in2    = (const float*)d_in[6];
    const float* g_in_w   = (const float*)d_in[7];
    const float* g_in_b   = (const float*)d_in[8];
    const float* A1       = (const float*)d_in[9];
    const float* A2       = (const float*)d_in[10];
    const float* W_out1   = (const float*)d_in[11];
    const float* b_out1   = (const float*)d_in[12];
    const float* W_out2   = (const float*)d_in[13];
    const float* b_out2   = (const float*)d_in[14];
    const float* g_out_w  = (const float*)d_in[15];
    const float* g_out_b  = (const float*)d_in[16];
    const float* B1       = (const float*)d_in[17];
    const float* B2       = (const float*)d_in[18];

    float* ws     = (float*)d_ws;
    float* t2a    = ws;              /* N*H = 65536 */
    float* fin    = ws + 65536;
    float* t2b    = ws + 131072;
    float* fout   = ws + 196608;
    float* stats1 = ws + 262144;     /* 8 floats */
    float* stats2 = ws + 262152;     /* 8 floats */
    float* out    = (float*)d_out;

    /* net_in */
    net2_kernel<IDIM><<<dim3(NPTS / 256), dim3(256), 0, stream>>>(
        features, W_in1, b_in1, W_in2, b_in2, t2a);
    gn_stats_kernel<<<dim3(4), dim3(256), 0, stream>>>(t2a, stats1);
    /* normalize -> fin, and zero fout for the atomic accumulation */
    gn_apply_kernel<<<dim3(NPTS * HDIM / 256), dim3(256), 0, stream>>>(
        t2a, stats1, g_in_w, g_in_b, fin, fout);

    /* all-pairs interaction */
    pairwise_kernel<<<dim3(16, 32), dim3(256), 0, stream>>>(
        points, nuv, A1, B1, A2, B2, fin, fout);

    /* net_out */
    net2_kernel<HDIM><<<dim3(NPTS / 256), dim3(256), 0, stream>>>(
        fout, W_out1, b_out1, W_out2, b_out2, t2b);
    gn_stats_kernel<<<dim3(4), dim3(256), 0, stream>>>(t2b, stats2);
    gn_apply_kernel<<<dim3(NPTS * HDIM / 256), dim3(256), 0, stream>>>(
        t2b, stats2, g_out_w, g_out_b, out, nullptr);
}